// Round 5
// baseline (168.450 us; speedup 1.0000x reference)
//
#include <hip/hip_runtime.h>
#include <hip/hip_bf16.h>

typedef unsigned short u16;
typedef short bf16x8 __attribute__((ext_vector_type(8)));
typedef float f32x4 __attribute__((ext_vector_type(4)));
typedef int   i32x4 __attribute__((ext_vector_type(4)));

#define NB 8
#define NT 1024
#define ND 512
#define KSEL 307
#define PSTR 152   // attn P LDS row stride (elems)
#define TSTR 136   // gemm_wh transpose LDS row stride (elems)

__device__ __forceinline__ float bf2f(u16 u){
  union { unsigned int i; float f; } c; c.i = ((unsigned int)u) << 16; return c.f;
}
__device__ __forceinline__ u16 f2bf(float f){
  __hip_bfloat16 h = __float2bfloat16(f);
  u16 u; __builtin_memcpy(&u, &h, 2); return u;
}

// ---------- prep: x f32 -> bf16 (+ row L2 norms), W -> Wbf[h*64+f][k] bf16,
//            W2 -> W2T[n][k] bf16, cn zeroing.
__global__ void k_prep(const float* __restrict__ x, const float* __restrict__ Wf,
                       const float* __restrict__ W2f, u16* __restrict__ xbf,
                       u16* __restrict__ WbT, u16* __restrict__ W2T,
                       float* __restrict__ mags, float* __restrict__ cn){
  __shared__ float tile[64][65];
  int bx = blockIdx.x;
  int tid = threadIdx.x;
  if (bx < 512){
    // x convert + mags: block handles 16 rows; one wave per 4 rows
    int wv = tid >> 6, lane = tid & 63;
#pragma unroll
    for (int rr = 0; rr < 4; rr++){
      int row = bx * 16 + wv * 4 + rr;
      const float* xp = &x[(size_t)row * 512 + lane * 8];
      f32x4 u0 = *(const f32x4*)xp;
      f32x4 u1 = *(const f32x4*)(xp + 4);
      u16 pk[8];
      float s = 0.f;
#pragma unroll
      for (int q = 0; q < 4; q++){
        s += u0[q]*u0[q] + u1[q]*u1[q];
        pk[q] = f2bf(u0[q]); pk[4+q] = f2bf(u1[q]);
      }
      *(bf16x8*)&xbf[(size_t)row * 512 + lane * 8] = *(const bf16x8*)pk;
#pragma unroll
      for (int m = 1; m < 64; m <<= 1) s += __shfl_xor(s, m, 64);
      if (lane == 0) mags[row] = sqrtf(s);
    }
  } else {
    // 64x64 f32 tile transpose-convert: 64 tiles for W, 64 for W2; + cn zero
    int tb = bx - 512;
    if (tb < 16) cn[tb * 256 + tid] = 0.f;
    const float* src; u16* dst; int srcld, dstld;
    if (tb < 64){
      int h = tb >> 3, kt = (tb & 7) * 64;
      src = Wf + ((size_t)h << 15) + (size_t)kt * 64;  srcld = 64;   // [k][f]
      dst = WbT + ((size_t)h * 64) * 512 + kt;         dstld = 512;  // [f][k]
    } else {
      int t2 = tb - 64;
      int kt = (t2 >> 3) * 64, n0 = (t2 & 7) * 64;
      src = W2f + (size_t)kt * 512 + n0;  srcld = 512;               // [k][n]
      dst = W2T + (size_t)n0 * 512 + kt;  dstld = 512;               // [n][k]
    }
    int r = tid >> 6, cl = tid & 63;
#pragma unroll
    for (int p = 0; p < 16; p++)
      tile[r + p*4][cl] = src[(size_t)(r + p*4) * srcld + cl];
    __syncthreads();
#pragma unroll
    for (int p = 0; p < 16; p++){
      int orow = r + p*4;                       // output row = source col
      dst[(size_t)orow * dstld + cl] = f2bf(tile[cl][orow]);
    }
  }
}

// ---------- exact top-k selection by ranking; 4 threads per t, 64 t per block
__global__ void k_select(const float* __restrict__ mags, int* __restrict__ sel){
  __shared__ float sm[NT];
  int b = blockIdx.x;
  int tid = threadIdx.x;
  for (int i = tid; i < NT; i += 256) sm[i] = mags[b * NT + i];
  __syncthreads();
  int tl = tid >> 2, tq = tid & 3;
  int t = blockIdx.y * 64 + tl;
  float m = sm[t];
  int cnt = 0;
  int s0 = tq * 256;
  for (int s = s0; s < s0 + 256; s++){
    float v = sm[s];
    cnt += (v > m) || (v == m && s < t);
  }
  cnt += __shfl_xor(cnt, 1, 64);
  cnt += __shfl_xor(cnt, 2, 64);
  if (tq == 0) sel[b * NT + t] = (cnt < KSEL) ? 1 : 0;
}

// ---------- MFMA bf16 GEMM: Wh = xbf @ Wbf^T ; tile 128(t) x 64(f = one head)
//   ZERO-LDS K-loop: direct bf16x8 fragment loads from xbf/Wbf (L1/L2-resident),
//   register prefetch of next K-step, no barriers. LDS only for epilogue transpose.
__launch_bounds__(256, 3)
__global__ void k_gemm_wh(const u16* __restrict__ xbf, const u16* __restrict__ Wbf,
                          const float* __restrict__ a_src, const float* __restrict__ a_dst,
                          u16* __restrict__ WhT, float* __restrict__ es, float* __restrict__ ed){
  __shared__ u16 Tr[64 * TSTR];      // 17408 B, epilogue-only
  int m0 = blockIdx.x * 128;         // t-block
  int h  = blockIdx.y;               // head (n0 = h*64)
  int tid = threadIdx.x;
  int wv = tid >> 6, lane = tid & 63;
  int quad = lane >> 4, lr = lane & 15;
  f32x4 acc[2][4] = {};
  const u16* ap = &xbf[(size_t)(m0 + wv*32 + lr) * 512 + quad*8];
  const u16* bp = &Wbf[(size_t)(h*64 + lr) * 512 + quad*8];
  bf16x8 ca0 = *(const bf16x8*)(ap);
  bf16x8 ca1 = *(const bf16x8*)(ap + 8192);
  bf16x8 cb0 = *(const bf16x8*)(bp);
  bf16x8 cb1 = *(const bf16x8*)(bp + 8192);
  bf16x8 cb2 = *(const bf16x8*)(bp + 16384);
  bf16x8 cb3 = *(const bf16x8*)(bp + 24576);
  for (int kt = 0; kt < 512; kt += 32){
    bf16x8 na0, na1, nb0, nb1, nb2, nb3;
    bool pf = kt < 480;
    if (pf){
      na0 = *(const bf16x8*)(ap + kt + 32);
      na1 = *(const bf16x8*)(ap + 8192 + kt + 32);
      nb0 = *(const bf16x8*)(bp + kt + 32);
      nb1 = *(const bf16x8*)(bp + 8192 + kt + 32);
      nb2 = *(const bf16x8*)(bp + 16384 + kt + 32);
      nb3 = *(const bf16x8*)(bp + 24576 + kt + 32);
    }
    acc[0][0] = __builtin_amdgcn_mfma_f32_16x16x32_bf16(ca0, cb0, acc[0][0], 0, 0, 0);
    acc[0][1] = __builtin_amdgcn_mfma_f32_16x16x32_bf16(ca0, cb1, acc[0][1], 0, 0, 0);
    acc[0][2] = __builtin_amdgcn_mfma_f32_16x16x32_bf16(ca0, cb2, acc[0][2], 0, 0, 0);
    acc[0][3] = __builtin_amdgcn_mfma_f32_16x16x32_bf16(ca0, cb3, acc[0][3], 0, 0, 0);
    acc[1][0] = __builtin_amdgcn_mfma_f32_16x16x32_bf16(ca1, cb0, acc[1][0], 0, 0, 0);
    acc[1][1] = __builtin_amdgcn_mfma_f32_16x16x32_bf16(ca1, cb1, acc[1][1], 0, 0, 0);
    acc[1][2] = __builtin_amdgcn_mfma_f32_16x16x32_bf16(ca1, cb2, acc[1][2], 0, 0, 0);
    acc[1][3] = __builtin_amdgcn_mfma_f32_16x16x32_bf16(ca1, cb3, acc[1][3], 0, 0, 0);
    if (pf){
      ca0 = na0; ca1 = na1;
      cb0 = nb0; cb1 = nb1; cb2 = nb2; cb3 = nb3;
    }
  }
  // ---- epilogue 1: edge dot products (wave owns rows wv*32..+32)
  float asv[4], adv[4];
#pragma unroll
  for (int ni = 0; ni < 4; ni++){
    asv[ni] = a_src[h*64 + ni*16 + lr];
    adv[ni] = a_dst[h*64 + ni*16 + lr];
  }
#pragma unroll
  for (int mi = 0; mi < 2; mi++)
#pragma unroll
    for (int r = 0; r < 4; r++){
      float pes = 0.f, ped = 0.f;
#pragma unroll
      for (int ni = 0; ni < 4; ni++){
        pes += acc[mi][ni][r] * asv[ni];
        ped += acc[mi][ni][r] * adv[ni];
      }
#pragma unroll
      for (int mofs = 1; mofs < 16; mofs <<= 1){
        pes += __shfl_xor(pes, mofs, 64);
        ped += __shfl_xor(ped, mofs, 64);
      }
      if (lr == 0){
        int rowg = m0 + wv*32 + mi*16 + quad*4 + r;
        int bb_ = rowg >> 10, tt = rowg & 1023;
        es[(bb_ * 8 + h) * NT + tt] = pes;
        ed[(bb_ * 8 + h) * NT + tt] = ped;
      }
    }
  // ---- epilogue 2: bf16 transpose via LDS -> WhT[(b*512 + h*64 + f)][t]
#pragma unroll
  for (int mi = 0; mi < 2; mi++)
#pragma unroll
    for (int ni = 0; ni < 4; ni++){
      int fl = ni*16 + lr;
      int tl = wv*32 + mi*16 + quad*4;
#pragma unroll
      for (int r = 0; r < 4; r++) Tr[fl*TSTR + tl + r] = f2bf(acc[mi][ni][r]);
    }
  __syncthreads();
  int f = tid >> 2, seg = tid & 3;
  int b_ = m0 >> 10;
  u16* dst = &WhT[(b_ * 512 + h * 64 + f) * NT + (m0 & 1023) + seg*32];
  const u16* srcp = &Tr[f*TSTR + seg*32];
#pragma unroll
  for (int k8 = 0; k8 < 4; k8++)
    *(bf16x8*)(dst + k8*8) = *(const bf16x8*)(srcp + k8*8);
}

// ---------- banded masked attention via MFMA + elu + signed-sqrt -> t2b (bf16)
//            + fused column sum-of-squares (atomicAdd into cn)
__launch_bounds__(256)
__global__ void k_attn(const u16* __restrict__ WhT, const float* __restrict__ es,
                       const float* __restrict__ ed, const int* __restrict__ sel,
                       u16* __restrict__ t2b, float* __restrict__ cn){
  __shared__ u16 P[64 * PSTR];
  __shared__ float edw[144];
  __shared__ int   selw[144];
  __shared__ float esw[64];
  __shared__ float swv[64];
  int bh = blockIdx.x;               // b*8+h
  int b = bh >> 3;
  int t0 = blockIdx.y * 64;
  int tid = threadIdx.x;
  int wv = tid >> 6, lane = tid & 63;
  int quad = lane >> 4, lr = lane & 15;
  int s_base = t0 - 40;
  for (int i = tid; i < 144; i += 256){
    int s = s_base + i;
    bool ok = (s >= 0 && s < NT);
    edw[i]  = ok ? ed[bh * NT + s] : 0.f;
    selw[i] = ok ? sel[b * NT + s] : 0;
  }
  if (tid < 64) esw[tid] = es[bh * NT + t0 + tid];
  {
    i32x4 z = {};
    for (int i = lane; i < 304; i += 64){
      int r16 = i / 19, c16 = i - r16 * 19;
      *(i32x4*)&P[(16*wv + r16) * PSTR + c16 * 8] = z;
    }
  }
  __syncthreads();
  {
    int tl = 16*wv + (lane >> 2);
    int q = lane & 3;
    float e_t = esw[tl];
    int sel_t = selw[tl + 40];
    float part = 0.f;
    for (int j = q; j <= 80; j += 4){
      int sw = tl + j;
      int s = s_base + sw;
      float w = 0.f;
      if (s >= 0 && s < NT && (sel_t | selw[sw])){
        float v = e_t + edw[sw];
        v = v > 0.f ? v : 0.2f * v;
        v = fminf(v, 60.f);
        w = bf2f(f2bf(__expf(v)));
      }
      part += w;
      if (w != 0.f) P[tl * PSTR + sw] = f2bf(w);
    }
    part += __shfl_xor(part, 1, 64);
    part += __shfl_xor(part, 2, 64);
    if (q == 0) swv[tl] = part;
  }
  __syncthreads();
  f32x4 acc[4] = {};
  const u16* vbase = WhT + (bh * 64) * NT;
#pragma unroll
  for (int ks = 0; ks < 96; ks += 32){
    bf16x8 afr = *(const bf16x8*)&P[(16*wv + lr) * PSTR + 16*wv + ks + quad*8];
    int tb = s_base + 16*wv + ks + quad*8;
    bool ok = (tb >= 0) && (tb < NT);
    bf16x8 zf = {};
#pragma unroll
    for (int jn = 0; jn < 4; jn++){
      bf16x8 bfr = ok ? *(const bf16x8*)&vbase[(16*jn + lr) * NT + tb] : zf;
      acc[jn] = __builtin_amdgcn_mfma_f32_16x16x32_bf16(afr, bfr, acc[jn], 0, 0, 0);
    }
  }
#pragma unroll
  for (int jn = 0; jn < 4; jn++){
    float ssum = 0.f;
#pragma unroll
    for (int r = 0; r < 4; r++){
      int t_loc = 16*wv + quad*4 + r;
      float sw_ = swv[t_loc];
      float hp = acc[jn][r] / (sw_ > 0.f ? sw_ : 1.f);
      hp = hp > 0.f ? hp : (__expf(hp) - 1.f);
      float o = hp >= 0.f ? sqrtf(hp) : -sqrtf(-hp);
      ssum += o * o;
      t2b[(b * NT + t0 + t_loc) * ND + (bh & 7) * 64 + 16*jn + lr] = f2bf(o);
    }
    ssum += __shfl_xor(ssum, 16, 64);
    ssum += __shfl_xor(ssum, 32, 64);
    if (quad == 0) atomicAdd(&cn[b * ND + (bh & 7) * 64 + 16*jn + lr], ssum);
  }
}

// ---------- GEMM2+LN fused: full-row tile 32(t) x 512(d), 512 threads, 256 blocks.
//   ZERO-LDS K-loop: A frags direct from t2b (scaled in regs via persistent scl LDS),
//   B frags direct from W2T. LN stats block-local; transposed f32 output.
__launch_bounds__(512)
__global__ void k_gemm2ln(const u16* __restrict__ A, const u16* __restrict__ W2T,
                          const float* __restrict__ xres, const float* __restrict__ b2,
                          const float* __restrict__ cn, const float* __restrict__ g,
                          const float* __restrict__ bb, float* __restrict__ out){
  __shared__ __align__(16) char smraw[69888];
  float* scl = (float*)smraw;             // 2048 B, K-loop only (aliases T)
  float* T     = (float*)smraw;           // [512 d][33] f32 = 67584 B, post-loop
  float* wpart = (float*)(smraw + 67584); // [2][8][32] = 2048 B
  float* mus   = (float*)(smraw + 69632); // 128 B
  float* rss   = (float*)(smraw + 69760); // 128 B
  int tid = threadIdx.x;
  int m0 = blockIdx.x * 32;               // global row base
  int b  = m0 >> 10, t0 = m0 & 1023;
  int w = tid >> 6, lane = tid & 63;
  int quad = lane >> 4, lr = lane & 15;
  {
    float nv = sqrtf(cn[(b << 9) + tid]);
    scl[tid] = 1.f / fmaxf(nv, 1e-12f);
  }
  __syncthreads();
  f32x4 acc[2][4] = {};
  const u16* ap = &A[(size_t)(m0 + lr) * 512 + quad*8];
  const u16* bp = &W2T[(size_t)(w*64 + lr) * 512 + quad*8];
  bf16x8 ca0 = *(const bf16x8*)(ap);
  bf16x8 ca1 = *(const bf16x8*)(ap + 8192);
  bf16x8 cb0 = *(const bf16x8*)(bp);
  bf16x8 cb1 = *(const bf16x8*)(bp + 8192);
  bf16x8 cb2 = *(const bf16x8*)(bp + 16384);
  bf16x8 cb3 = *(const bf16x8*)(bp + 24576);
  for (int kt = 0; kt < 512; kt += 32){
    bf16x8 na0, na1, nb0, nb1, nb2, nb3;
    bool pf = kt < 480;
    if (pf){
      na0 = *(const bf16x8*)(ap + kt + 32);
      na1 = *(const bf16x8*)(ap + 8192 + kt + 32);
      nb0 = *(const bf16x8*)(bp + kt + 32);
      nb1 = *(const bf16x8*)(bp + 8192 + kt + 32);
      nb2 = *(const bf16x8*)(bp + 16384 + kt + 32);
      nb3 = *(const bf16x8*)(bp + 24576 + kt + 32);
    }
    // scale A frags by scl[k] (LDS broadcast reads)
    f32x4 s0 = *(const f32x4*)&scl[kt + quad*8];
    f32x4 s1 = *(const f32x4*)&scl[kt + quad*8 + 4];
    bf16x8 af0, af1;
    {
      u16 pk0[8], pk1[8];
#pragma unroll
      for (int q = 0; q < 4; q++){
        pk0[q]   = f2bf(bf2f((u16)ca0[q])   * s0[q]);
        pk0[4+q] = f2bf(bf2f((u16)ca0[4+q]) * s1[q]);
        pk1[q]   = f2bf(bf2f((u16)ca1[q])   * s0[q]);
        pk1[4+q] = f2bf(bf2f((u16)ca1[4+q]) * s1[q]);
      }
      af0 = *(const bf16x8*)pk0;
      af1 = *(const bf16x8*)pk1;
    }
    acc[0][0] = __builtin_amdgcn_mfma_f32_16x16x32_bf16(af0, cb0, acc[0][0], 0, 0, 0);
    acc[0][1] = __builtin_amdgcn_mfma_f32_16x16x32_bf16(af0, cb1, acc[0][1], 0, 0, 0);
    acc[0][2] = __builtin_amdgcn_mfma_f32_16x16x32_bf16(af0, cb2, acc[0][2], 0, 0, 0);
    acc[0][3] = __builtin_amdgcn_mfma_f32_16x16x32_bf16(af0, cb3, acc[0][3], 0, 0, 0);
    acc[1][0] = __builtin_amdgcn_mfma_f32_16x16x32_bf16(af1, cb0, acc[1][0], 0, 0, 0);
    acc[1][1] = __builtin_amdgcn_mfma_f32_16x16x32_bf16(af1, cb1, acc[1][1], 0, 0, 0);
    acc[1][2] = __builtin_amdgcn_mfma_f32_16x16x32_bf16(af1, cb2, acc[1][2], 0, 0, 0);
    acc[1][3] = __builtin_amdgcn_mfma_f32_16x16x32_bf16(af1, cb3, acc[1][3], 0, 0, 0);
    if (pf){
      ca0 = na0; ca1 = na1;
      cb0 = nb0; cb1 = nb1; cb2 = nb2; cb3 = nb3;
    }
  }
  // ---- epilogue: yv = acc + xres + b2 ; block-local LN stats
  float b2v[4];
#pragma unroll
  for (int ni = 0; ni < 4; ni++) b2v[ni] = b2[w*64 + ni*16 + lr];
  float yv[2][4][4];
#pragma unroll
  for (int mi = 0; mi < 2; mi++)
#pragma unroll
    for (int r = 0; r < 4; r++){
      int rl = mi*16 + quad*4 + r;
      float rs = 0.f, rq = 0.f;
#pragma unroll
      for (int ni = 0; ni < 4; ni++){
        int col = w*64 + ni*16 + lr;
        float v = acc[mi][ni][r] + xres[(size_t)(m0 + rl) * 512 + col] + b2v[ni];
        yv[mi][ni][r] = v;
        rs += v; rq += v * v;
      }
#pragma unroll
      for (int m2 = 1; m2 < 16; m2 <<= 1){
        rs += __shfl_xor(rs, m2, 64);
        rq += __shfl_xor(rq, m2, 64);
      }
      if (lr == 0){
        wpart[w*32 + rl]       = rs;
        wpart[256 + w*32 + rl] = rq;
      }
    }
  __syncthreads();     // wpart ready; scl (aliased by T) is dead from here
  if (tid < 32){
    float s = 0.f, q = 0.f;
#pragma unroll
    for (int wv2 = 0; wv2 < 8; wv2++){
      s += wpart[wv2*32 + tid];
      q += wpart[256 + wv2*32 + tid];
    }
    float mu = s * (1.f/512.f);
    float var = q * (1.f/512.f) - mu * mu;
    mus[tid] = mu;
    rss[tid] = 1.f / sqrtf(var + 1e-5f);
  }
  __syncthreads();
  // normalize into transpose tile T[d][t]
  float gv[4], bv[4];
#pragma unroll
  for (int ni = 0; ni < 4; ni++){
    gv[ni] = g[w*64 + ni*16 + lr];
    bv[ni] = bb[w*64 + ni*16 + lr];
  }
#pragma unroll
  for (int mi = 0; mi < 2; mi++)
#pragma unroll
    for (int r = 0; r < 4; r++){
      int rl = mi*16 + quad*4 + r;
      float mu = mus[rl], rstd = rss[rl];
#pragma unroll
      for (int ni = 0; ni < 4; ni++){
        int col = w*64 + ni*16 + lr;
        T[col*33 + rl] = (yv[mi][ni][r] - mu) * rstd * gv[ni] + bv[ni];
      }
    }
  __syncthreads();
  // write out[B,D,T]: 128 B contiguous per d
  int j = tid & 31, dq = tid >> 5;
#pragma unroll
  for (int kk2 = 0; kk2 < 32; kk2++){
    int d = dq + kk2 * 16;
    out[((size_t)(b * 512 + d)) * 1024 + t0 + j] = T[d*33 + j];
  }
}

extern "C" void kernel_launch(void* const* d_in, const int* in_sizes, int n_in,
                              void* d_out, int out_size, void* d_ws, size_t ws_size,
                              hipStream_t stream) {
  (void)in_sizes; (void)n_in; (void)out_size; (void)ws_size;
  const float* x     = (const float*)d_in[0];
  const float* W     = (const float*)d_in[1];
  const float* a_src = (const float*)d_in[2];
  const float* a_dst = (const float*)d_in[3];
  const float* W2    = (const float*)d_in[4];
  const float* b2    = (const float*)d_in[5];
  const float* ln_g  = (const float*)d_in[6];
  const float* ln_b  = (const float*)d_in[7];
  char* ws = (char*)d_ws;
  int*   sel   = (int*)  (ws + 256);
  float* mags  = (float*)(ws + 33024);
  float* es    = (float*)(ws + 1124608);
  float* ed    = (float*)(ws + 1386752);
  float* cn    = (float*)(ws + 1648896);   // 16 KB (zeroed in k_prep)
  u16*   WhT   = (u16*)  (ws + 2097152);   // 8 MB; dead after k_attn
  u16*   t2b   = (u16*)  (ws + 18874368);  // 8 MB
  u16*   xbf   = (u16*)  (ws + 27262976);  // 8 MB bf16(x)
  u16*   Wbf   = (u16*)  (ws + 35651584);  // 512 KB bf16 W[h*64+f][k]
  u16*   W2T   = (u16*)  (ws + 36175872);  // 512 KB bf16 W2[n][k]
  float* out   = (float*)d_out;

  k_prep     <<<dim3(640), 256, 0, stream>>>(x, W, W2, xbf, Wbf, W2T, mags, cn);
  k_select   <<<dim3(NB, 16), 256, 0, stream>>>(mags, sel);
  k_gemm_wh  <<<dim3(64, 8), 256, 0, stream>>>(xbf, Wbf, a_src, a_dst, WhT, es, ed);
  k_attn     <<<dim3(64, 16), 256, 0, stream>>>(WhT, es, ed, sel, t2b, cn);
  k_gemm2ln  <<<dim3(256), 512, 0, stream>>>(t2b, W2T, x, b2, cn, ln_g, ln_b, out);
}

// Round 6
// 144.560 us; speedup vs baseline: 1.1653x; 1.1653x over previous
//
#include <hip/hip_runtime.h>
#include <hip/hip_bf16.h>

typedef unsigned short u16;
typedef short bf16x8 __attribute__((ext_vector_type(8)));
typedef short u16x4 __attribute__((ext_vector_type(4)));
typedef float f32x4 __attribute__((ext_vector_type(4)));
typedef int   i32x4 __attribute__((ext_vector_type(4)));

#define NB 8
#define NT 1024
#define ND 512
#define KSEL 307
#define PSTR 152   // attn P LDS row stride (elems)
#define TSTR 136   // gemm_wh transpose LDS row stride (elems)

__device__ __forceinline__ float bf2f(u16 u){
  union { unsigned int i; float f; } c; c.i = ((unsigned int)u) << 16; return c.f;
}
__device__ __forceinline__ u16 f2bf(float f){
  __hip_bfloat16 h = __float2bfloat16(f);
  u16 u; __builtin_memcpy(&u, &h, 2); return u;
}

// ---------- exact top-k selection by ranking; 4 threads per t, 64 t per block
__global__ void k_select(const float* __restrict__ mags, int* __restrict__ sel){
  __shared__ float sm[NT];
  int b = blockIdx.x;
  int tid = threadIdx.x;
  for (int i = tid; i < NT; i += 256) sm[i] = mags[b * NT + i];
  __syncthreads();
  int tl = tid >> 2, tq = tid & 3;
  int t = blockIdx.y * 64 + tl;
  float m = sm[t];
  int cnt = 0;
  int s0 = tq * 256;
  for (int s = s0; s < s0 + 256; s++){
    float v = sm[s];
    cnt += (v > m) || (v == m && s < t);
  }
  cnt += __shfl_xor(cnt, 1, 64);
  cnt += __shfl_xor(cnt, 2, 64);
  if (tq == 0) sel[b * NT + t] = (cnt < KSEL) ? 1 : 0;
}

// ---------- MFMA bf16 GEMM: Wh = bf16(x) @ W ; tile 128(t) x 128(f = head PAIR)
//   512 threads, grid (64 t-blocks, 4 head-pairs). Halves x re-staging vs 64-f tile.
//   Fused: cn zero (hp==0), W2->bf16 W2T[n][k] transpose (hp==1 pre-phase),
//          mags epilogue (hp==0), es/ed edge dots (both heads), WhT write.
__launch_bounds__(512, 2)
__global__ void k_gemm_wh(const float* __restrict__ x, const float* __restrict__ Wf,
                          const float* __restrict__ W2f,
                          const float* __restrict__ a_src, const float* __restrict__ a_dst,
                          u16* __restrict__ WhT, float* __restrict__ es, float* __restrict__ ed,
                          float* __restrict__ mags, float* __restrict__ cn,
                          u16* __restrict__ W2T){
  __shared__ u16 smem[17408];        // 34816 B; As(5120)+Bs(5120) alias Tr(128*TSTR) / f32 tile
  u16* As = smem;                    // 128 x 40
  u16* Bs = smem + 5120;             // 128 x 40 (k-chunks xor-swizzled)
  int m0 = blockIdx.x * 128;         // t-block
  int hp = blockIdx.y;               // head pair (heads hp*2, hp*2+1)
  int tid = threadIdx.x;
  // fused zero-init: cn consumed by k_attn
  if (hp == 0 && tid < 64) cn[blockIdx.x * 64 + tid] = 0.f;
  // fused W2 transpose-convert: 64 tiles of 64x64, one per hp==1 block
  if (hp == 1){
    float* tile = (float*)smem;      // 64*65*4 = 16640 B <= 34816
    int kt0 = (blockIdx.x >> 3) * 64, n00 = (blockIdx.x & 7) * 64;
    int r = tid >> 6, cl = tid & 63; // r 0..7
#pragma unroll
    for (int p = 0; p < 8; p++)
      tile[(r + p*8)*65 + cl] = W2f[(size_t)(kt0 + r + p*8) * 512 + n00 + cl];
    __syncthreads();
#pragma unroll
    for (int p = 0; p < 8; p++){
      int orow = r + p*8;            // n-local
      W2T[(size_t)(n00 + orow) * 512 + kt0 + cl] = f2bf(tile[cl*65 + orow]);
    }
    __syncthreads();
  }
  int wv = tid >> 6, lane = tid & 63;        // wv 0..7
  int quad = lane >> 4, lr = lane & 15;
  f32x4 acc[8] = {};
  float sq = 0.f;
  // A addressing: 128 rows x 32 k, 512 threads x 8 elems
  int ar = tid >> 2, ac = (tid & 3) * 8;
  const float* xa = &x[(size_t)(m0 + ar) * 512 + ac];
  // B addressing: 128 f x 32 k; f0 mult of 8, kk 0..31
  int f0 = (tid * 8) & 127, kk = (tid * 8) >> 7;
  int hh = hp * 2 + (f0 >> 6), fl0 = f0 & 63;
  const float* wb = &Wf[((size_t)hh << 15) + (size_t)kk * 64 + fl0];
  int bbase = f0 * 40 + (((kk >> 3) ^ ((f0 >> 3) & 3)) * 8) + (kk & 7);
  f32x4 pa0 = *(const f32x4*)xa, pa1 = *(const f32x4*)(xa + 4);
  f32x4 pb0 = *(const f32x4*)wb, pb1 = *(const f32x4*)(wb + 4);
  for (int kt = 0; kt < 512; kt += 32){
    __syncthreads();
    {
      u16 pk[8];
      if (hp == 0){
#pragma unroll
        for (int q = 0; q < 4; q++) sq += pa0[q]*pa0[q] + pa1[q]*pa1[q];
      }
#pragma unroll
      for (int q = 0; q < 4; q++){ pk[q] = f2bf(pa0[q]); pk[4+q] = f2bf(pa1[q]); }
      *(bf16x8*)&As[ar*40 + ac] = *(const bf16x8*)pk;
#pragma unroll
      for (int q = 0; q < 4; q++) Bs[bbase + q*40]     = f2bf(pb0[q]);
#pragma unroll
      for (int q = 0; q < 4; q++) Bs[bbase + (q+4)*40] = f2bf(pb1[q]);
    }
    __syncthreads();
    if (kt < 480){
      pa0 = *(const f32x4*)(xa + kt + 32); pa1 = *(const f32x4*)(xa + kt + 36);
      pb0 = *(const f32x4*)(wb + (size_t)(kt + 32) * 64);
      pb1 = *(const f32x4*)(wb + (size_t)(kt + 32) * 64 + 4);
    }
    bf16x8 af = *(const bf16x8*)&As[(wv*16 + lr)*40 + quad*8];
#pragma unroll
    for (int ni = 0; ni < 8; ni++){
      int f = ni*16 + lr;
      bf16x8 bfr = *(const bf16x8*)&Bs[f*40 + ((quad ^ ((f >> 3) & 3)) * 8)];
      acc[ni] = __builtin_amdgcn_mfma_f32_16x16x32_bf16(af, bfr, acc[ni], 0, 0, 0);
    }
  }
  // ---- epilogue 0: row L2 norms (4 threads per row), hp==0 blocks only
  if (hp == 0){
    float s = sq;
    s += __shfl_xor(s, 1, 64);
    s += __shfl_xor(s, 2, 64);
    if ((tid & 3) == 0) mags[m0 + (tid >> 2)] = sqrtf(s);
  }
  // ---- epilogue 1: edge dot products (both heads; wave owns rows wv*16..+16)
  float asv[8], adv[8];
#pragma unroll
  for (int ni = 0; ni < 8; ni++){
    asv[ni] = a_src[hp*128 + ni*16 + lr];
    adv[ni] = a_dst[hp*128 + ni*16 + lr];
  }
#pragma unroll
  for (int r = 0; r < 4; r++){
    float pes0 = 0.f, ped0 = 0.f, pes1 = 0.f, ped1 = 0.f;
#pragma unroll
    for (int ni = 0; ni < 4; ni++){
      pes0 += acc[ni][r] * asv[ni];
      ped0 += acc[ni][r] * adv[ni];
      pes1 += acc[ni+4][r] * asv[ni+4];
      ped1 += acc[ni+4][r] * adv[ni+4];
    }
#pragma unroll
    for (int mofs = 1; mofs < 16; mofs <<= 1){
      pes0 += __shfl_xor(pes0, mofs, 64);
      ped0 += __shfl_xor(ped0, mofs, 64);
      pes1 += __shfl_xor(pes1, mofs, 64);
      ped1 += __shfl_xor(ped1, mofs, 64);
    }
    if (lr == 0){
      int rowg = m0 + wv*16 + quad*4 + r;
      int bb_ = rowg >> 10, tt = rowg & 1023;
      es[(bb_ * 8 + hp*2) * NT + tt]     = pes0;
      ed[(bb_ * 8 + hp*2) * NT + tt]     = ped0;
      es[(bb_ * 8 + hp*2 + 1) * NT + tt] = pes1;
      ed[(bb_ * 8 + hp*2 + 1) * NT + tt] = ped1;
    }
  }
  // ---- epilogue 2: bf16 transpose via LDS -> WhT[(b*512 + hp*128 + f)][t]
  __syncthreads();
  u16* Tr = smem;   // [f 0..127][t 0..127], stride TSTR
#pragma unroll
  for (int ni = 0; ni < 8; ni++){
    int fl = ni*16 + lr;
    int tl = wv*16 + quad*4;
    u16 pk[4];
#pragma unroll
    for (int r = 0; r < 4; r++) pk[r] = f2bf(acc[ni][r]);
    *(u16x4*)&Tr[fl*TSTR + tl] = *(const u16x4*)pk;
  }
  __syncthreads();
  int f = tid >> 2, seg = tid & 3;
  int b_ = m0 >> 10;
  u16* dst = &WhT[((size_t)b_ * 512 + hp * 128 + f) * NT + (m0 & 1023) + seg*32];
  const u16* srcp = &Tr[f*TSTR + seg*32];
#pragma unroll
  for (int k8 = 0; k8 < 4; k8++)
    *(bf16x8*)(dst + k8*8) = *(const bf16x8*)(srcp + k8*8);
}

// ---------- banded masked attention via MFMA + elu + signed-sqrt -> t2b (bf16)
//            + fused column sum-of-squares (atomicAdd into cn)
__launch_bounds__(256)
__global__ void k_attn(const u16* __restrict__ WhT, const float* __restrict__ es,
                       const float* __restrict__ ed, const int* __restrict__ sel,
                       u16* __restrict__ t2b, float* __restrict__ cn){
  __shared__ u16 P[64 * PSTR];
  __shared__ float edw[144];
  __shared__ int   selw[144];
  __shared__ float esw[64];
  __shared__ float swv[64];
  int bh = blockIdx.x;               // b*8+h
  int b = bh >> 3;
  int t0 = blockIdx.y * 64;
  int tid = threadIdx.x;
  int wv = tid >> 6, lane = tid & 63;
  int quad = lane >> 4, lr = lane & 15;
  int s_base = t0 - 40;
  for (int i = tid; i < 144; i += 256){
    int s = s_base + i;
    bool ok = (s >= 0 && s < NT);
    edw[i]  = ok ? ed[bh * NT + s] : 0.f;
    selw[i] = ok ? sel[b * NT + s] : 0;
  }
  if (tid < 64) esw[tid] = es[bh * NT + t0 + tid];
  {
    i32x4 z = {};
    for (int i = lane; i < 304; i += 64){
      int r16 = i / 19, c16 = i - r16 * 19;
      *(i32x4*)&P[(16*wv + r16) * PSTR + c16 * 8] = z;
    }
  }
  __syncthreads();
  {
    int tl = 16*wv + (lane >> 2);
    int q = lane & 3;
    float e_t = esw[tl];
    int sel_t = selw[tl + 40];
    float part = 0.f;
    for (int j = q; j <= 80; j += 4){
      int sw = tl + j;
      int s = s_base + sw;
      float w = 0.f;
      if (s >= 0 && s < NT && (sel_t | selw[sw])){
        float v = e_t + edw[sw];
        v = v > 0.f ? v : 0.2f * v;
        v = fminf(v, 60.f);
        w = bf2f(f2bf(__expf(v)));
      }
      part += w;
      if (w != 0.f) P[tl * PSTR + sw] = f2bf(w);
    }
    part += __shfl_xor(part, 1, 64);
    part += __shfl_xor(part, 2, 64);
    if (q == 0) swv[tl] = part;
  }
  __syncthreads();
  f32x4 acc[4] = {};
  const u16* vbase = WhT + (bh * 64) * NT;
#pragma unroll
  for (int ks = 0; ks < 96; ks += 32){
    bf16x8 afr = *(const bf16x8*)&P[(16*wv + lr) * PSTR + 16*wv + ks + quad*8];
    int tb = s_base + 16*wv + ks + quad*8;
    bool ok = (tb >= 0) && (tb < NT);
    bf16x8 zf = {};
#pragma unroll
    for (int jn = 0; jn < 4; jn++){
      bf16x8 bfr = ok ? *(const bf16x8*)&vbase[(16*jn + lr) * NT + tb] : zf;
      acc[jn] = __builtin_amdgcn_mfma_f32_16x16x32_bf16(afr, bfr, acc[jn], 0, 0, 0);
    }
  }
#pragma unroll
  for (int jn = 0; jn < 4; jn++){
    float ssum = 0.f;
#pragma unroll
    for (int r = 0; r < 4; r++){
      int t_loc = 16*wv + quad*4 + r;
      float sw_ = swv[t_loc];
      float hp = acc[jn][r] / (sw_ > 0.f ? sw_ : 1.f);
      hp = hp > 0.f ? hp : (__expf(hp) - 1.f);
      float o = hp >= 0.f ? sqrtf(hp) : -sqrtf(-hp);
      ssum += o * o;
      t2b[(b * NT + t0 + t_loc) * ND + (bh & 7) * 64 + 16*jn + lr] = f2bf(o);
    }
    ssum += __shfl_xor(ssum, 16, 64);
    ssum += __shfl_xor(ssum, 32, 64);
    if (quad == 0) atomicAdd(&cn[b * ND + (bh & 7) * 64 + 16*jn + lr], ssum);
  }
}

// ---------- GEMM2+LN fused: full-row tile 32(t) x 512(d), 512 threads, 256 blocks.
//   Y = (t2b*scl) @ W2 + x + b2 computed in regs; LN stats block-local;
//   normalized output written transposed ([B,D,T]) via LDS tile. No Y/rsum/rqsum.
__launch_bounds__(512)
__global__ void k_gemm2ln(const u16* __restrict__ A, const u16* __restrict__ W2T,
                          const float* __restrict__ xres, const float* __restrict__ b2,
                          const float* __restrict__ cn, const float* __restrict__ g,
                          const float* __restrict__ bb, float* __restrict__ out){
  __shared__ __align__(16) char smraw[69888];
  u16*   As  = (u16*)smraw;               // 32 x 40 = 2560 B
  u16*   Bs  = (u16*)(smraw + 2560);      // 512 x 40 = 40960 B (end 43520)
  float* scl = (float*)(smraw + 43520);   // 2048 B (end 45568)
  // post-K-loop aliases:
  float* T     = (float*)smraw;           // [512 d][33] f32 = 67584 B
  float* wpart = (float*)(smraw + 67584); // [2][8][32] = 2048 B
  float* mus   = (float*)(smraw + 69632); // 128 B
  float* rss   = (float*)(smraw + 69760); // 128 B
  int tid = threadIdx.x;
  int m0 = blockIdx.x * 32;               // global row base
  int b  = m0 >> 10, t0 = m0 & 1023;
  int w = tid >> 6, lane = tid & 63;
  int quad = lane >> 4, lr = lane & 15;
  // scl
  {
    float nv = sqrtf(cn[(b << 9) + tid]);
    scl[tid] = 1.f / fmaxf(nv, 1e-12f);
  }
  // staging prefetch (kt = 0)
  int ar = tid >> 2, ac = (tid & 3) * 8;        // A: threads 0..127
  const u16* ap = &A[(size_t)(m0 + ar) * 512 + ac];
  int nb_ = tid >> 2, c = (tid & 3) * 8;        // B: all threads, 4 reps
  bf16x8 ra = {}, rb[4];
  if (tid < 128) ra = *(const bf16x8*)ap;
#pragma unroll
  for (int rep = 0; rep < 4; rep++)
    rb[rep] = *(const bf16x8*)&W2T[(size_t)(nb_ + rep*128) * 512 + c];
  f32x4 acc[2][4] = {};
  for (int kt = 0; kt < 512; kt += 32){
    __syncthreads();
    if (tid < 128){
      u16 pk[8];
#pragma unroll
      for (int q = 0; q < 8; q++)
        pk[q] = f2bf(bf2f((u16)ra[q]) * scl[kt + ac + q]);
      *(bf16x8*)&As[ar*40 + ac] = *(const bf16x8*)pk;
    }
#pragma unroll
    for (int rep = 0; rep < 4; rep++)
      *(bf16x8*)&Bs[(nb_ + rep*128)*40 + c] = rb[rep];
    __syncthreads();
    if (kt < 480){
      if (tid < 128) ra = *(const bf16x8*)(ap + kt + 32);
#pragma unroll
      for (int rep = 0; rep < 4; rep++)
        rb[rep] = *(const bf16x8*)&W2T[(size_t)(nb_ + rep*128) * 512 + kt + 32 + c];
    }
    bf16x8 af[2], bfr[4];
#pragma unroll
    for (int mi = 0; mi < 2; mi++) af[mi] = *(const bf16x8*)&As[(mi*16 + lr)*40 + quad*8];
#pragma unroll
    for (int i = 0; i < 4; i++)
      bfr[i] = *(const bf16x8*)&Bs[(w*64 + i*16 + lr)*40 + quad*8];
#pragma unroll
    for (int mi = 0; mi < 2; mi++)
#pragma unroll
      for (int ni = 0; ni < 4; ni++)
        acc[mi][ni] = __builtin_amdgcn_mfma_f32_16x16x32_bf16(af[mi], bfr[ni], acc[mi][ni], 0, 0, 0);
  }
  // ---- epilogue: yv = acc + xres + b2 ; block-local LN stats
  float b2v[4];
#pragma unroll
  for (int ni = 0; ni < 4; ni++) b2v[ni] = b2[w*64 + ni*16 + lr];
  float yv[2][4][4];
#pragma unroll
  for (int mi = 0; mi < 2; mi++)
#pragma unroll
    for (int r = 0; r < 4; r++){
      int rl = mi*16 + quad*4 + r;
      float rs = 0.f, rq = 0.f;
#pragma unroll
      for (int ni = 0; ni < 4; ni++){
        int col = w*64 + ni*16 + lr;
        float v = acc[mi][ni][r] + xres[(size_t)(m0 + rl) * 512 + col] + b2v[ni];
        yv[mi][ni][r] = v;
        rs += v; rq += v * v;
      }
#pragma unroll
      for (int m2 = 1; m2 < 16; m2 <<= 1){
        rs += __shfl_xor(rs, m2, 64);
        rq += __shfl_xor(rq, m2, 64);
      }
      if (lr == 0){
        wpart[w*32 + rl]       = rs;
        wpart[256 + w*32 + rl] = rq;
      }
    }
  __syncthreads();     // wpart ready; all staging-LDS reads done
  if (tid < 32){
    float s = 0.f, q = 0.f;
#pragma unroll
    for (int wv2 = 0; wv2 < 8; wv2++){
      s += wpart[wv2*32 + tid];
      q += wpart[256 + wv2*32 + tid];
    }
    float mu = s * (1.f/512.f);
    float var = q * (1.f/512.f) - mu * mu;
    mus[tid] = mu;
    rss[tid] = 1.f / sqrtf(var + 1e-5f);
  }
  __syncthreads();
  // normalize into transpose tile T[d][t]
  float gv[4], bv[4];
#pragma unroll
  for (int ni = 0; ni < 4; ni++){
    gv[ni] = g[w*64 + ni*16 + lr];
    bv[ni] = bb[w*64 + ni*16 + lr];
  }
#pragma unroll
  for (int mi = 0; mi < 2; mi++)
#pragma unroll
    for (int r = 0; r < 4; r++){
      int rl = mi*16 + quad*4 + r;
      float mu = mus[rl], rstd = rss[rl];
#pragma unroll
      for (int ni = 0; ni < 4; ni++){
        int col = w*64 + ni*16 + lr;
        T[col*33 + rl] = (yv[mi][ni][r] - mu) * rstd * gv[ni] + bv[ni];
      }
    }
  __syncthreads();
  // write out[B,D,T]: 128 B contiguous per d
  int j = tid & 31, dq = tid >> 5;
#pragma unroll
  for (int kk2 = 0; kk2 < 32; kk2++){
    int d = dq + kk2 * 16;
    out[((size_t)(b * 512 + d)) * 1024 + t0 + j] = T[d*33 + j];
  }
}

extern "C" void kernel_launch(void* const* d_in, const int* in_sizes, int n_in,
                              void* d_out, int out_size, void* d_ws, size_t ws_size,
                              hipStream_t stream) {
  (void)in_sizes; (void)n_in; (void)out_size; (void)ws_size;
  const float* x     = (const float*)d_in[0];
  const float* W     = (const float*)d_in[1];
  const float* a_src = (const float*)d_in[2];
  const float* a_dst = (const float*)d_in[3];
  const float* W2    = (const float*)d_in[4];
  const float* b2    = (const float*)d_in[5];
  const float* ln_g  = (const float*)d_in[6];
  const float* ln_b  = (const float*)d_in[7];
  char* ws = (char*)d_ws;
  int*   sel   = (int*)  (ws + 256);
  float* mags  = (float*)(ws + 33024);
  float* es    = (float*)(ws + 1124608);
  float* ed    = (float*)(ws + 1386752);
  float* cn    = (float*)(ws + 1648896);   // 16 KB (zeroed in k_gemm_wh hp==0 blocks)
  u16*   WhT   = (u16*)  (ws + 2097152);   // 8 MB; dead after k_attn
  u16*   t2b   = (u16*)  (ws + 18874368);  // 8 MB
  u16*   W2T   = (u16*)  (ws + 36175872);  // 512 KB bf16 W2[n][k] (written by k_gemm_wh hp==1)
  float* out   = (float*)d_out;

  k_gemm_wh  <<<dim3(64, 4), 512, 0, stream>>>(x, W, W2, a_src, a_dst, WhT, es, ed, mags, cn, W2T);
  k_select   <<<dim3(NB, 16), 256, 0, stream>>>(mags, sel);
  k_attn     <<<dim3(64, 16), 256, 0, stream>>>(WhT, es, ed, sel, t2b, cn);
  k_gemm2ln  <<<dim3(256), 512, 0, stream>>>(t2b, W2T, x, b2, cn, ln_g, ln_b, out);
}